// Round 8
// baseline (199.401 us; speedup 1.0000x reference)
//
#include <hip/hip_runtime.h>
#include <hip/hip_bf16.h>

// ---------------------------------------------------------------------------
// CVXPolicy_DoubleIntegrator, R10: max independent-chain multiplicity.
//
// R2-R9 refuted: occupancy(R3/R5), lockstep(R6), z-prefetch(R7), LDS
// round-trip(R8), ds_read amortization(R9) — duration pinned at ~65us across
// all of them, all pipes <21% busy. The never-varied axis: INDEPENDENT work
// units per SIMD. All clean variants ran 2 waves/SIMD, each one long serial
// chain. R10: transposed bt=2 flow (R8-verified math), ZERO LDS (weights +
// biases straight from L2 — 96KB resident), ZERO barriers, 256-thr blocks,
// grid 1024 = 4 blocks/CU = 16 waves/CU = 4 independent chains/SIMD, with
// launch_bounds(256,4) -> VGPR cap 128 (bt=2 fits: ~120 peak).
//
// Packed weights (bf16, scatter folded into W3, t-row of W1 removed):
//   PW1: frag (kt*7+nt), kt<6, nt<7        -> shorts [0, 21504)
//   PW2: frag 42+kt*7+nt, kt<4, nt<7       -> shorts [21504, 35840)
//   PW3: frag 70+kt*6+nt, kt<4, nt<6       -> shorts [35840, 48128)
//   floats at short-index 48128: w0[112], b1[112], b2[112], bq[96]
// frag = 512 shorts: element e = lane*8+j -> W[k = kt*32+(lane>>4)*8+j][n = nt*16+(lane&15)]
//   (as A-operand this reads W^T[m=nt*16+l15][k] — what the transposed flow needs)
//
// MFMA 16x16x32 bf16 layouts (verified R1):
//   A:   lane -> A[m = lane&15][k = (lane>>4)*8 + j]
//   B:   lane -> B[k = (lane>>4)*8 + j][n = lane&15]
//   C/D: lane -> col = lane&15, row = (lane>>4)*4 + reg
// C->next-B rebuild (verified R8/R9 pass): cvt_pk pairs + shfl from lanes
//   lo_src = 2*(qd&1)*16 + l15, hi_src = lo_src+16, lane<32 selects even nt.
// ---------------------------------------------------------------------------

typedef __attribute__((ext_vector_type(8))) short short8;
typedef __attribute__((ext_vector_type(4))) float f32x4;

__device__ __forceinline__ unsigned short f2bf(float f) {
  unsigned u = __float_as_uint(f);
  u += 0x7fffu + ((u >> 16) & 1u);  // RNE (finite values only)
  return (unsigned short)(u >> 16);
}
__device__ __forceinline__ float tanh_fast(float x) {
  // tanh(x) = 1 - 2/(exp(2x)+1); exp2 overflow -> inf -> rcp -> 0 -> 1. 5 ops.
  float e = __builtin_amdgcn_exp2f(x * 2.88539008177792681f);
  return fmaf(-2.f, __builtin_amdgcn_rcpf(e + 1.f), 1.f);
}
__device__ __forceinline__ short8 pack_bf8(f32x4 a, f32x4 b) {
  union { short8 s; __hip_bfloat162 h[4]; } u;
  u.h[0] = __float22bfloat162_rn(make_float2(a[0], a[1]));
  u.h[1] = __float22bfloat162_rn(make_float2(a[2], a[3]));
  u.h[2] = __float22bfloat162_rn(make_float2(b[0], b[1]));
  u.h[3] = __float22bfloat162_rn(make_float2(b[2], b[3]));
  return u.s;
}
__device__ __forceinline__ unsigned pk2u(float lo, float hi) {
  union { __hip_bfloat162 h; unsigned u; } x;
  x.h = __float22bfloat162_rn(make_float2(lo, hi));
  return x.u;
}

// ---------------------------------------------------------------------------
// Prep: pack weights bf16, fold scatter into W3, drop t-row (kept as w0 f32).
// (unchanged from R2..R9)
// ---------------------------------------------------------------------------
__global__ void cvx_prep(const float* __restrict__ W1, const float* __restrict__ b1,
                         const float* __restrict__ W2, const float* __restrict__ b2,
                         const float* __restrict__ W3, const float* __restrict__ b3,
                         short* __restrict__ pw) {
  int idx = blockIdx.x * 256 + threadIdx.x;

  if (idx < 21504) {                        // PW1: 6 kt * 7 nt * 512
    int kt = idx / 3584, rem = idx % 3584;
    int nt = rem / 512, e = rem % 512;
    int lane = e >> 3, j = e & 7;
    int k = kt * 32 + (lane >> 4) * 8 + j;  // z index; W1 row k+1
    int n = nt * 16 + (lane & 15);
    float wv = (n < 100) ? W1[(k + 1) * 100 + n] : 0.f;
    pw[(kt * 7 + nt) * 512 + e] = (short)f2bf(wv);
    return;
  }
  idx -= 21504;
  if (idx < 14336) {                        // PW2: 4 kt * 7 nt * 512
    int kt = idx / 3584, rem = idx % 3584;
    int nt = rem / 512, e = rem % 512;
    int lane = e >> 3, j = e & 7;
    int k = kt * 32 + (lane >> 4) * 8 + j;
    int n = nt * 16 + (lane & 15);
    float wv = (k < 100 && n < 100) ? W2[k * 100 + n] : 0.f;
    pw[21504 + (kt * 7 + nt) * 512 + e] = (short)f2bf(wv);
    return;
  }
  idx -= 14336;
  if (idx < 12288) {                        // PW3 folded: 4 kt * 6 nt * 512
    int kt = idx / 3072, rem = idx % 3072;
    int nt = rem / 512, e = rem % 512;
    int lane = e >> 3, j = e & 7;
    int k = kt * 32 + (lane >> 4) * 8 + j;
    int u = nt * 16 + (lane & 15);          // u < 96
    float wv = 0.f;
    if (k < 100) {
      const float* wr = W3 + k * 192;
      if (u <= 31) wv += wr[3 * u + 3];                     // u = i
      if ((u & 1) == 0 && u <= 62) wv += wr[2 * u + 4];     // u = 2i
      if (u % 3 == 0 && u <= 93) wv += wr[(5 * u) / 3 + 5]; // u = 3i
    }
    pw[35840 + (kt * 6 + nt) * 512 + e] = (short)f2bf(wv);
    return;
  }
  idx -= 12288;
  float* cb = (float*)(pw + 48128);
  if (idx < 112) { cb[idx] = (idx < 100) ? W1[idx] : 0.f; return; }        // w0 = W1 row 0
  idx -= 112;
  if (idx < 112) { cb[112 + idx] = (idx < 100) ? b1[idx] : 0.f; return; }
  idx -= 112;
  if (idx < 112) { cb[224 + idx] = (idx < 100) ? b2[idx] : 0.f; return; }
  idx -= 112;
  if (idx < 96) {
    int u = idx;
    float v = 0.f;
    if (u <= 31) v += b3[3 * u + 3];
    if ((u & 1) == 0 && u <= 62) v += b3[2 * u + 4];
    if (u % 3 == 0 && u <= 93) v += b3[(5 * u) / 3 + 5];
    cb[336 + u] = v;
  }
}

// ---------------------------------------------------------------------------
// Main fused kernel: 256 thr (4 waves), grid 1024 = 4 blocks/CU = 16 waves/CU,
// 32 rows/wave, zero LDS, zero barriers. Transposed dataflow.
// ---------------------------------------------------------------------------
__global__ __launch_bounds__(256, 4) void cvx_main(
    const float* __restrict__ zin, const float* __restrict__ tin,
    const short* __restrict__ pw, float* __restrict__ out) {
  const int tid = threadIdx.x;
  const int wid = tid >> 6;
  const int lane = tid & 63;
  const int l15 = lane & 15;
  const int qd = lane >> 4;
  // qd-permutation sources for C->B-frag rebuild:
  const int lo_src = ((lane & 16) << 1) + l15;  // lane of qd'' = 2*(qd&1)
  const int hi_src = lo_src + 16;               // lane of qd'' = 2*(qd&1)+1
  const bool selA = lane < 32;                  // qd<2 -> even nt source

  const int row0 = blockIdx.x * 128 + wid * 32;
  const short* wfrag = pw + lane * 8;           // per-lane base for fragments
  const float* cb = (const float*)(pw + 48128); // biases (L2-resident)

  // z,t -> bf16 B-fragments (Z^T), 2 batch-tiles
  short8 XB[2][6];
  float tc[2];
#pragma unroll
  for (int bt = 0; bt < 2; bt++) {
    const float* zr = zin + (size_t)(row0 + bt * 16 + l15) * 192 + qd * 8;
#pragma unroll
    for (int kt = 0; kt < 6; kt++) {
      f32x4 a = *(const f32x4*)(zr + kt * 32);
      f32x4 b = *(const f32x4*)(zr + kt * 32 + 4);
      XB[bt][kt] = pack_bf8(a, b);
    }
    tc[bt] = tin[row0 + bt * 16 + l15];
  }

  // rebuild one B-fragment of H^T (K-tile kt) from packed C-layout regs.
  auto buildHB = [&](const unsigned (&pkb)[7][2], int kt) -> short8 {
    union { short8 s; unsigned u[4]; } hb;
    if (kt < 3) {
      unsigned a0 = (unsigned)__shfl((int)pkb[2 * kt][0], lo_src);
      unsigned b0 = (unsigned)__shfl((int)pkb[2 * kt + 1][0], lo_src);
      unsigned a1 = (unsigned)__shfl((int)pkb[2 * kt][1], lo_src);
      unsigned b1_ = (unsigned)__shfl((int)pkb[2 * kt + 1][1], lo_src);
      unsigned a2 = (unsigned)__shfl((int)pkb[2 * kt][0], hi_src);
      unsigned b2_ = (unsigned)__shfl((int)pkb[2 * kt + 1][0], hi_src);
      unsigned a3 = (unsigned)__shfl((int)pkb[2 * kt][1], hi_src);
      unsigned b3_ = (unsigned)__shfl((int)pkb[2 * kt + 1][1], hi_src);
      hb.u[0] = selA ? a0 : b0;
      hb.u[1] = selA ? a1 : b1_;
      hb.u[2] = selA ? a2 : b2_;
      hb.u[3] = selA ? a3 : b3_;
    } else {  // k in [96,112) real (nt'=6); [112,128) garbage x zero-W = safe
      hb.u[0] = (unsigned)__shfl((int)pkb[6][0], lo_src);
      hb.u[1] = (unsigned)__shfl((int)pkb[6][1], lo_src);
      hb.u[2] = (unsigned)__shfl((int)pkb[6][0], hi_src);
      hb.u[3] = (unsigned)__shfl((int)pkb[6][1], hi_src);
    }
    return hb.s;
  };

  // ---- Layer 1: S1^T = W1^T (A, from L2) x Z^T (B) ----
  f32x4 acc[2][7];
#pragma unroll
  for (int nt = 0; nt < 7; nt++) {
    f32x4 zzz = {0.f, 0.f, 0.f, 0.f};
    acc[0][nt] = zzz; acc[1][nt] = zzz;
  }
#pragma unroll
  for (int kt = 0; kt < 6; kt++)
#pragma unroll
    for (int nt = 0; nt < 7; nt++) {
      short8 wf = *(const short8*)(wfrag + (kt * 7 + nt) * 512);
      acc[0][nt] = __builtin_amdgcn_mfma_f32_16x16x32_bf16(wf, XB[0][kt], acc[0][nt], 0, 0, 0);
      acc[1][nt] = __builtin_amdgcn_mfma_f32_16x16x32_bf16(wf, XB[1][kt], acc[1][nt], 0, 0, 0);
    }

  // ---- L1 epilogue: + t*w0 + b1 -> tanh -> pack (all in registers) ----
  unsigned pk[2][7][2];
#pragma unroll
  for (int bt = 0; bt < 2; bt++)
#pragma unroll
    for (int nt = 0; nt < 7; nt++) {
      f32x4 w0v = *(const f32x4*)&cb[nt * 16 + qd * 4];
      f32x4 b1v = *(const f32x4*)&cb[112 + nt * 16 + qd * 4];
#pragma unroll
      for (int r = 0; r < 4; r++)
        acc[bt][nt][r] = tanh_fast(fmaf(tc[bt], w0v[r], acc[bt][nt][r] + b1v[r]));
      pk[bt][nt][0] = pk2u(acc[bt][nt][0], acc[bt][nt][1]);
      pk[bt][nt][1] = pk2u(acc[bt][nt][2], acc[bt][nt][3]);
    }

  // ---- Layer 2: S2^T = W2^T x H1^T ----
#pragma unroll
  for (int nt = 0; nt < 7; nt++) {
    f32x4 zzz = {0.f, 0.f, 0.f, 0.f};
    acc[0][nt] = zzz; acc[1][nt] = zzz;
  }
#pragma unroll
  for (int kt = 0; kt < 4; kt++) {
    short8 hb0 = buildHB(pk[0], kt);
    short8 hb1 = buildHB(pk[1], kt);
#pragma unroll
    for (int nt = 0; nt < 7; nt++) {
      short8 wf = *(const short8*)(wfrag + (42 + kt * 7 + nt) * 512);
      acc[0][nt] = __builtin_amdgcn_mfma_f32_16x16x32_bf16(wf, hb0, acc[0][nt], 0, 0, 0);
      acc[1][nt] = __builtin_amdgcn_mfma_f32_16x16x32_bf16(wf, hb1, acc[1][nt], 0, 0, 0);
    }
  }
  // L2 epilogue: + b2 -> tanh -> repack
#pragma unroll
  for (int bt = 0; bt < 2; bt++)
#pragma unroll
    for (int nt = 0; nt < 7; nt++) {
      f32x4 b2v = *(const f32x4*)&cb[224 + nt * 16 + qd * 4];
#pragma unroll
      for (int r = 0; r < 4; r++)
        acc[bt][nt][r] = tanh_fast(acc[bt][nt][r] + b2v[r]);
      pk[bt][nt][0] = pk2u(acc[bt][nt][0], acc[bt][nt][1]);
      pk[bt][nt][1] = pk2u(acc[bt][nt][2], acc[bt][nt][3]);
    }

  // ---- Layer 3 (scatter-folded): Q^T = W3f^T x H2^T ----
  f32x4 qa[2][6];
#pragma unroll
  for (int nt = 0; nt < 6; nt++) {
    f32x4 zzz = {0.f, 0.f, 0.f, 0.f};
    qa[0][nt] = zzz; qa[1][nt] = zzz;
  }
#pragma unroll
  for (int kt = 0; kt < 4; kt++) {
    short8 hb0 = buildHB(pk[0], kt);
    short8 hb1 = buildHB(pk[1], kt);
#pragma unroll
    for (int nt = 0; nt < 6; nt++) {
      short8 wf = *(const short8*)(wfrag + (70 + kt * 6 + nt) * 512);
      qa[0][nt] = __builtin_amdgcn_mfma_f32_16x16x32_bf16(wf, hb0, qa[0][nt], 0, 0, 0);
      qa[1][nt] = __builtin_amdgcn_mfma_f32_16x16x32_bf16(wf, hb1, qa[1][nt], 0, 0, 0);
    }
  }

  // ---- QP epilogue (lane = batch row row0 + bt*16 + l15; u = nt*16+qd*4+r) ----
#pragma unroll
  for (int bt = 0; bt < 2; bt++) {
#pragma unroll
    for (int nt = 0; nt < 6; nt++) {
      f32x4 bqv = *(const f32x4*)&cb[336 + nt * 16 + qd * 4];
      qa[bt][nt] += bqv;
    }
    float loc = 0.f;
#pragma unroll
    for (int nt = 0; nt < 6; nt++) {
      f32x4 q = qa[bt][nt];
      loc += q[0] * q[0] + q[1] * q[1] + q[2] * q[2] + q[3] * q[3];
    }
    loc += __shfl_xor(loc, 16);
    loc += __shfl_xor(loc, 32);     // full ||q||^2 for this row on all 4 qd lanes
    float r2 = loc;
    float s = __builtin_amdgcn_exp2f(__builtin_amdgcn_logf(r2) * 0.333333333333f);
#pragma unroll
    for (int itn = 0; itn < 8; itn++) {
      float one = 1.f + s;
      float fv = fmaf(s * one, one, -r2);
      float fp = one * fmaf(2.f, s, one);
      s = fmaxf(s - fv * __builtin_amdgcn_rcpf(fp), 0.f);
    }
    float inv = -__builtin_amdgcn_rcpf(1.f + s);
    float* orow = out + (size_t)(row0 + bt * 16 + l15) * 96;
#pragma unroll
    for (int nt = 0; nt < 6; nt++) {
      f32x4 v = qa[bt][nt] * inv;
      *(f32x4*)(orow + nt * 16 + qd * 4) = v;   // 16 rows x 64B, coalesced
    }
  }
}

extern "C" void kernel_launch(void* const* d_in, const int* in_sizes, int n_in,
                              void* d_out, int out_size, void* d_ws, size_t ws_size,
                              hipStream_t stream) {
  const float* z  = (const float*)d_in[0];
  const float* t  = (const float*)d_in[1];
  const float* W1 = (const float*)d_in[2];
  const float* b1 = (const float*)d_in[3];
  const float* W2 = (const float*)d_in[4];
  const float* b2 = (const float*)d_in[5];
  const float* W3 = (const float*)d_in[6];
  const float* b3 = (const float*)d_in[7];
  float* out = (float*)d_out;
  int B = in_sizes[0] / 192;                 // 131072

  short* pw = (short*)d_ws;                  // 97,984 bytes used
  cvx_prep<<<190, 256, 0, stream>>>(W1, b1, W2, b2, W3, b3, pw);
  cvx_main<<<B / 128, 256, 0, stream>>>(z, t, pw, out);
}

// Round 10
// 185.531 us; speedup vs baseline: 1.0748x; 1.0748x over previous
//
#include <hip/hip_runtime.h>
#include <hip/hip_bf16.h>

// ---------------------------------------------------------------------------
// CVXPolicy_DoubleIntegrator, R11 (resubmit — round 9 was an infra failure,
// "MI355X container failed twice"; kernel untested, theory unchanged).
//
// COMPACT HOT LOOP — 4 iterations of a ~7KB body instead of a one-shot ~14KB
// straight-line chain.
//
// R2-R10 refuted: occupancy, blocks/CU, lockstep-stagger, z-prefetch(+3us),
// LDS h round-trip, ds_read amortization, independent-chain multiplicity —
// duration pinned 63-74us, all pipes <21% busy. The never-varied constant:
// every variant was a ONE-SHOT unrolled body per wave (no I$ temporal reuse,
// no cross-iteration pipelining). R11: transposed bt=1 flow (16 rows/wave/
// iter), 4-iteration loop, weights in LDS (consistently ~4us better than L2),
// z prefetched one iteration ahead (R7-proven, sched_barrier-pinned).
// grid 256 x 512thr (8 waves, 1 block/CU), launch_bounds(512,2) -> 128 VGPR.
//
// Packed weights (bf16, scatter folded into W3, t-row of W1 removed):
//   PW1: frag (kt*7+nt), kt<6, nt<7        -> shorts [0, 21504)
//   PW2: frag 42+kt*7+nt, kt<4, nt<7       -> shorts [21504, 35840)
//   PW3: frag 70+kt*6+nt, kt<4, nt<6       -> shorts [35840, 48128)
//   floats at short-index 48128: w0[112], b1[112], b2[112], bq[96]
// frag = 512 shorts: element e = lane*8+j -> W[k = kt*32+(lane>>4)*8+j][n = nt*16+(lane&15)]
//   (as A-operand this reads W^T[m=nt*16+l15][k] — what the transposed flow needs)
//
// MFMA 16x16x32 bf16 layouts (verified R1):
//   A:   lane -> A[m = lane&15][k = (lane>>4)*8 + j]
//   B:   lane -> B[k = (lane>>4)*8 + j][n = lane&15]
//   C/D: lane -> col = lane&15, row = (lane>>4)*4 + reg
// C->next-B rebuild (verified R8/R9/R10 pass): cvt_pk pairs + shfl from lanes
//   lo_src = 2*(qd&1)*16 + l15, hi_src = lo_src+16, lane<32 selects even nt.
// ---------------------------------------------------------------------------

typedef __attribute__((ext_vector_type(8))) short short8;
typedef __attribute__((ext_vector_type(4))) float f32x4;

__device__ __forceinline__ unsigned short f2bf(float f) {
  unsigned u = __float_as_uint(f);
  u += 0x7fffu + ((u >> 16) & 1u);  // RNE (finite values only)
  return (unsigned short)(u >> 16);
}
__device__ __forceinline__ float tanh_fast(float x) {
  // tanh(x) = 1 - 2/(exp(2x)+1); exp2 overflow -> inf -> rcp -> 0 -> 1. 5 ops.
  float e = __builtin_amdgcn_exp2f(x * 2.88539008177792681f);
  return fmaf(-2.f, __builtin_amdgcn_rcpf(e + 1.f), 1.f);
}
__device__ __forceinline__ short8 pack_bf8(f32x4 a, f32x4 b) {
  union { short8 s; __hip_bfloat162 h[4]; } u;
  u.h[0] = __float22bfloat162_rn(make_float2(a[0], a[1]));
  u.h[1] = __float22bfloat162_rn(make_float2(a[2], a[3]));
  u.h[2] = __float22bfloat162_rn(make_float2(b[0], b[1]));
  u.h[3] = __float22bfloat162_rn(make_float2(b[2], b[3]));
  return u.s;
}
__device__ __forceinline__ unsigned pk2u(float lo, float hi) {
  union { __hip_bfloat162 h; unsigned u; } x;
  x.h = __float22bfloat162_rn(make_float2(lo, hi));
  return x.u;
}

// ---------------------------------------------------------------------------
// Prep: pack weights bf16, fold scatter into W3, drop t-row (kept as w0 f32).
// (unchanged from R2..R10)
// ---------------------------------------------------------------------------
__global__ void cvx_prep(const float* __restrict__ W1, const float* __restrict__ b1,
                         const float* __restrict__ W2, const float* __restrict__ b2,
                         const float* __restrict__ W3, const float* __restrict__ b3,
                         short* __restrict__ pw) {
  int idx = blockIdx.x * 256 + threadIdx.x;

  if (idx < 21504) {                        // PW1: 6 kt * 7 nt * 512
    int kt = idx / 3584, rem = idx % 3584;
    int nt = rem / 512, e = rem % 512;
    int lane = e >> 3, j = e & 7;
    int k = kt * 32 + (lane >> 4) * 8 + j;  // z index; W1 row k+1
    int n = nt * 16 + (lane & 15);
    float wv = (n < 100) ? W1[(k + 1) * 100 + n] : 0.f;
    pw[(kt * 7 + nt) * 512 + e] = (short)f2bf(wv);
    return;
  }
  idx -= 21504;
  if (idx < 14336) {                        // PW2: 4 kt * 7 nt * 512
    int kt = idx / 3584, rem = idx % 3584;
    int nt = rem / 512, e = rem % 512;
    int lane = e >> 3, j = e & 7;
    int k = kt * 32 + (lane >> 4) * 8 + j;
    int n = nt * 16 + (lane & 15);
    float wv = (k < 100 && n < 100) ? W2[k * 100 + n] : 0.f;
    pw[21504 + (kt * 7 + nt) * 512 + e] = (short)f2bf(wv);
    return;
  }
  idx -= 14336;
  if (idx < 12288) {                        // PW3 folded: 4 kt * 6 nt * 512
    int kt = idx / 3072, rem = idx % 3072;
    int nt = rem / 512, e = rem % 512;
    int lane = e >> 3, j = e & 7;
    int k = kt * 32 + (lane >> 4) * 8 + j;
    int u = nt * 16 + (lane & 15);          // u < 96
    float wv = 0.f;
    if (k < 100) {
      const float* wr = W3 + k * 192;
      if (u <= 31) wv += wr[3 * u + 3];                     // u = i
      if ((u & 1) == 0 && u <= 62) wv += wr[2 * u + 4];     // u = 2i
      if (u % 3 == 0 && u <= 93) wv += wr[(5 * u) / 3 + 5]; // u = 3i
    }
    pw[35840 + (kt * 6 + nt) * 512 + e] = (short)f2bf(wv);
    return;
  }
  idx -= 12288;
  float* cb = (float*)(pw + 48128);
  if (idx < 112) { cb[idx] = (idx < 100) ? W1[idx] : 0.f; return; }        // w0 = W1 row 0
  idx -= 112;
  if (idx < 112) { cb[112 + idx] = (idx < 100) ? b1[idx] : 0.f; return; }
  idx -= 112;
  if (idx < 112) { cb[224 + idx] = (idx < 100) ? b2[idx] : 0.f; return; }
  idx -= 112;
  if (idx < 96) {
    int u = idx;
    float v = 0.f;
    if (u <= 31) v += b3[3 * u + 3];
    if ((u & 1) == 0 && u <= 62) v += b3[2 * u + 4];
    if (u % 3 == 0 && u <= 93) v += b3[(5 * u) / 3 + 5];
    cb[336 + u] = v;
  }
}

// ---------------------------------------------------------------------------
// Main fused kernel: 512 thr (8 waves), grid 256 = 1 block/CU, 4-iteration
// loop, 16 rows/wave/iteration. Weights in LDS. Transposed dataflow.
// ---------------------------------------------------------------------------
__global__ __launch_bounds__(512, 2) void cvx_main(
    const float* __restrict__ zin, const float* __restrict__ tin,
    const short* __restrict__ pw, float* __restrict__ out) {
  __shared__ __align__(16) short wbuf[48128];  // 96,256 B: all weights
  __shared__ __align__(16) float cbl[448];     // 1,792 B: w0|b1|b2|bq

  const int tid = threadIdx.x;
  const int wid = tid >> 6;
  const int lane = tid & 63;
  const int l15 = lane & 15;
  const int qd = lane >> 4;
  // qd-permutation sources for C->B-frag rebuild:
  const int lo_src = ((lane & 16) << 1) + l15;  // lane of qd'' = 2*(qd&1)
  const int hi_src = lo_src + 16;               // lane of qd'' = 2*(qd&1)+1
  const bool selA = lane < 32;                  // qd<2 -> even nt source

  // stage ALL weights into LDS (once per block)
  for (int f = wid; f < 94; f += 8) {
    const short* g = pw + f * 512 + lane * 8;
    __builtin_amdgcn_global_load_lds(
        (const __attribute__((address_space(1))) void*)g,
        (__attribute__((address_space(3))) void*)&wbuf[f * 512], 16, 0, 0);
  }
  if (tid < 448) cbl[tid] = ((const float*)(pw + 48128))[tid];

  const int rowb = blockIdx.x * 512;

  // prologue: issue iteration-0 z,t loads (overlap weight staging; the
  // barrier's vmcnt(0) drain covers them)
  f32x4 sga[6], sgb[6];
  float tld;
  {
    const float* zr = zin + (size_t)(rowb + wid * 16 + l15) * 192 + qd * 8;
#pragma unroll
    for (int kt = 0; kt < 6; kt++) {
      sga[kt] = *(const f32x4*)(zr + kt * 32);
      sgb[kt] = *(const f32x4*)(zr + kt * 32 + 4);
    }
    tld = tin[rowb + wid * 16 + l15];
  }

  __syncthreads();  // the only barrier

  // rebuild one B-fragment of H^T (K-tile kt) from packed C-layout regs.
  auto buildHB = [&](const unsigned (&pkb)[7][2], int kt) -> short8 {
    union { short8 s; unsigned u[4]; } hb;
    if (kt < 3) {
      unsigned a0 = (unsigned)__shfl((int)pkb[2 * kt][0], lo_src);
      unsigned b0 = (unsigned)__shfl((int)pkb[2 * kt + 1][0], lo_src);
      unsigned a1 = (unsigned)__shfl((int)pkb[2 * kt][1], lo_src);
      unsigned b1_ = (unsigned)__shfl((int)pkb[2 * kt + 1][1], lo_src);
      unsigned a2 = (unsigned)__shfl((int)pkb[2 * kt][0], hi_src);
      unsigned b2_ = (unsigned)__shfl((int)pkb[2 * kt + 1][0], hi_src);
      unsigned a3 = (unsigned)__shfl((int)pkb[2 * kt][1], hi_src);
      unsigned b3_ = (unsigned)__shfl((int)pkb[2 * kt + 1][1], hi_src);
      hb.u[0] = selA ? a0 : b0;
      hb.u[1] = selA ? a1 : b1_;
      hb.u[2] = selA ? a2 : b2_;
      hb.u[3] = selA ? a3 : b3_;
    } else {  // k in [96,112) real (nt'=6); [112,128) garbage x zero-W = safe
      hb.u[0] = (unsigned)__shfl((int)pkb[6][0], lo_src);
      hb.u[1] = (unsigned)__shfl((int)pkb[6][1], lo_src);
      hb.u[2] = (unsigned)__shfl((int)pkb[6][0], hi_src);
      hb.u[3] = (unsigned)__shfl((int)pkb[6][1], hi_src);
    }
    return hb.s;
  };

#pragma unroll 1
  for (int it = 0; it < 4; ++it) {
    const int row0 = rowb + it * 128 + wid * 16;

    // ---- pack this iteration's B-fragments from staged regs ----
    short8 XB[6];
#pragma unroll
    for (int kt = 0; kt < 6; kt++) XB[kt] = pack_bf8(sga[kt], sgb[kt]);
    float tc = tld;

    // ---- issue next iteration's z,t loads (hide under this iter's compute)
    if (it < 3) {
      const float* zr = zin + (size_t)(row0 + 128 + l15) * 192 + qd * 8;
#pragma unroll
      for (int kt = 0; kt < 6; kt++) {
        sga[kt] = *(const f32x4*)(zr + kt * 32);
        sgb[kt] = *(const f32x4*)(zr + kt * 32 + 4);
      }
      tld = tin[row0 + 128 + l15];
      __builtin_amdgcn_sched_barrier(0);
    }

    // ---- Layer 1: S1^T = W1^T (A, LDS) x Z^T (B) ----
    f32x4 acc[7];
#pragma unroll
    for (int nt = 0; nt < 7; nt++) {
      f32x4 zzz = {0.f, 0.f, 0.f, 0.f};
      acc[nt] = zzz;
    }
#pragma unroll
    for (int kt = 0; kt < 6; kt++)
#pragma unroll
      for (int nt = 0; nt < 7; nt++) {
        short8 wf = *(const short8*)&wbuf[(kt * 7 + nt) * 512 + lane * 8];
        acc[nt] = __builtin_amdgcn_mfma_f32_16x16x32_bf16(wf, XB[kt], acc[nt], 0, 0, 0);
      }

    // ---- L1 epilogue: + t*w0 + b1 -> tanh -> pack ----
    unsigned pk[7][2];
#pragma unroll
    for (int nt = 0; nt < 7; nt++) {
      f32x4 w0v = *(const f32x4*)&cbl[nt * 16 + qd * 4];
      f32x4 b1v = *(const f32x4*)&cbl[112 + nt * 16 + qd * 4];
#pragma unroll
      for (int r = 0; r < 4; r++)
        acc[nt][r] = tanh_fast(fmaf(tc, w0v[r], acc[nt][r] + b1v[r]));
      pk[nt][0] = pk2u(acc[nt][0], acc[nt][1]);
      pk[nt][1] = pk2u(acc[nt][2], acc[nt][3]);
    }

    // ---- Layer 2: S2^T = W2^T x H1^T ----
#pragma unroll
    for (int nt = 0; nt < 7; nt++) {
      f32x4 zzz = {0.f, 0.f, 0.f, 0.f};
      acc[nt] = zzz;
    }
#pragma unroll
    for (int kt = 0; kt < 4; kt++) {
      short8 hb = buildHB(pk, kt);
#pragma unroll
      for (int nt = 0; nt < 7; nt++) {
        short8 wf = *(const short8*)&wbuf[(42 + kt * 7 + nt) * 512 + lane * 8];
        acc[nt] = __builtin_amdgcn_mfma_f32_16x16x32_bf16(wf, hb, acc[nt], 0, 0, 0);
      }
    }
    // L2 epilogue: + b2 -> tanh -> repack
#pragma unroll
    for (int nt = 0; nt < 7; nt++) {
      f32x4 b2v = *(const f32x4*)&cbl[224 + nt * 16 + qd * 4];
#pragma unroll
      for (int r = 0; r < 4; r++)
        acc[nt][r] = tanh_fast(acc[nt][r] + b2v[r]);
      pk[nt][0] = pk2u(acc[nt][0], acc[nt][1]);
      pk[nt][1] = pk2u(acc[nt][2], acc[nt][3]);
    }

    // ---- Layer 3 (scatter-folded): Q^T = W3f^T x H2^T ----
    f32x4 qa[6];
#pragma unroll
    for (int nt = 0; nt < 6; nt++) {
      f32x4 zzz = {0.f, 0.f, 0.f, 0.f};
      qa[nt] = zzz;
    }
#pragma unroll
    for (int kt = 0; kt < 4; kt++) {
      short8 hb = buildHB(pk, kt);
#pragma unroll
      for (int nt = 0; nt < 6; nt++) {
        short8 wf = *(const short8*)&wbuf[(70 + kt * 6 + nt) * 512 + lane * 8];
        qa[nt] = __builtin_amdgcn_mfma_f32_16x16x32_bf16(wf, hb, qa[nt], 0, 0, 0);
      }
    }

    // ---- QP epilogue (lane = batch row row0 + l15; u = nt*16+qd*4+r) ----
#pragma unroll
    for (int nt = 0; nt < 6; nt++) {
      f32x4 bqv = *(const f32x4*)&cbl[336 + nt * 16 + qd * 4];
      qa[nt] += bqv;
    }
    float loc = 0.f;
#pragma unroll
    for (int nt = 0; nt < 6; nt++) {
      f32x4 q = qa[nt];
      loc += q[0] * q[0] + q[1] * q[1] + q[2] * q[2] + q[3] * q[3];
    }
    loc += __shfl_xor(loc, 16);
    loc += __shfl_xor(loc, 32);     // full ||q||^2 for this row on all 4 qd lanes
    float r2 = loc;
    float s = __builtin_amdgcn_exp2f(__builtin_amdgcn_logf(r2) * 0.333333333333f);
#pragma unroll
    for (int itn = 0; itn < 8; itn++) {
      float one = 1.f + s;
      float fv = fmaf(s * one, one, -r2);
      float fp = one * fmaf(2.f, s, one);
      s = fmaxf(s - fv * __builtin_amdgcn_rcpf(fp), 0.f);
    }
    float inv = -__builtin_amdgcn_rcpf(1.f + s);
    float* orow = out + (size_t)(row0 + l15) * 96;
#pragma unroll
    for (int nt = 0; nt < 6; nt++) {
      f32x4 v = qa[nt] * inv;
      *(f32x4*)(orow + nt * 16 + qd * 4) = v;   // 16 rows x 64B, coalesced
    }
  }
}

extern "C" void kernel_launch(void* const* d_in, const int* in_sizes, int n_in,
                              void* d_out, int out_size, void* d_ws, size_t ws_size,
                              hipStream_t stream) {
  const float* z  = (const float*)d_in[0];
  const float* t  = (const float*)d_in[1];
  const float* W1 = (const float*)d_in[2];
  const float* b1 = (const float*)d_in[3];
  const float* W2 = (const float*)d_in[4];
  const float* b2 = (const float*)d_in[5];
  const float* W3 = (const float*)d_in[6];
  const float* b3 = (const float*)d_in[7];
  float* out = (float*)d_out;
  int B = in_sizes[0] / 192;                 // 131072

  short* pw = (short*)d_ws;                  // 97,984 bytes used
  cvx_prep<<<190, 256, 0, stream>>>(W1, b1, W2, b2, W3, b3, pw);
  cvx_main<<<B / 512, 512, 0, stream>>>(z, t, pw, out);
}